// Round 4
// baseline (246.952 us; speedup 1.0000x reference)
//
#include <hip/hip_runtime.h>
#include <math.h>

// LinearAttend: B=4, N=8, D=64, S=8192, fp32 in/out.
// out[j,s] = (QSCALE/W_s) * sum_i (ctx[i,j]/Z_i) * exp(q[i,s])
//   ctx[i,j] = sum_s exp(k[i,s]) * v[j,s],  Z_i = sum_s exp(k[i,s])
// 3-kernel pipeline, zero atomics:
//   1) ctx_partial: 32-way split-K fp16-MFMA partials. T14 async-staged
//      double-buffered LDS tiles (K,V fp32 [64][32], XOR slot-swizzled):
//      issue next tile's 16 KB of global loads -> compute current tile
//      from LDS -> vmcnt-wait + ds_write + ONE barrier. Bytes-in-flight
//      per block 16 KB (was ~2.5 KB reg-pipeline): the kernel is
//      MLP-bound (rounds 1-3: ~1.4 TB/s at ~1.6 KB/CU in flight,
//      residency pinned ~2.5 blocks/CU regardless of grid).
//      V staged once per block (kills the 4x per-wave L1 re-read).
//   2) reduce: 512 blocks, sum 32 chunk-partials, fold 1/Z, fp16 czT[j][i].
//   3) out: 32x32x16 fp16 MFMA -> full-cacheline stores (unchanged).

typedef _Float16 half8 __attribute__((ext_vector_type(8)));
typedef float floatx4 __attribute__((ext_vector_type(4)));
typedef float floatx16 __attribute__((ext_vector_type(16)));

constexpr int BHEADS = 32;
constexpr int DH     = 64;
constexpr int SEQ    = 8192;
constexpr int NCHUNK = 32;          // split-K chunks of 256 s
constexpr float QSCALE = 0.125f;    // 64^-0.5

// ---------------------------------------------------------------------------
// Kernel 1: partial[head][chunk][i][j] = sum_{s in chunk} e[i,s]*v[j,s]
//           Zp[head][chunk][i]         = sum_{s in chunk} e[i,s]
// grid (32 chunks x 32 heads) = 1024 blocks x 256 threads (4 waves).
// Wave w owns i-rows [16w,16w+16) over the FULL 256-s chunk (no merge).
// 8 K-steps of BK=32 s. Per step:
//   1. issue step t+1 global loads (4 float4/thread, 16 KB/block)
//   2. compute step t from LDS buf p (ds_read fp32, exp, cvt, 4 MFMA/wave)
//   3. ds_write staged regs -> buf p^1 (swizzled), __syncthreads
// LDS tiles [64 rows][32 floats], 128 B rows, 16B-slot swizzle
//   slot' = slot ^ (row & 7)  (write-side AND read-side; reg-staged so
//   both sides can swizzle - rule #21 satisfied).
// Fragment map (16x16x32 f16): lane = ln + 16*q8 holds
//   A[m=ln][k=q8*8..+8) = exp(K[16w+ln][s0+st*32+q8*8..])
//   B[n=ln][k=...]      =      V[16jt+ln][s0+st*32+q8*8..]
//   C/D: col=ln, row=q8*4+reg   [m89/m91 verified layout]
// ---------------------------------------------------------------------------
__global__ __launch_bounds__(256)
void ctx_partial_kernel(const float* __restrict__ K, const float* __restrict__ V,
                        float* __restrict__ partial, float* __restrict__ Zp)
{
    const int head  = blockIdx.y;
    const int chunk = blockIdx.x;
    const int t     = threadIdx.x;
    const int lane  = t & 63;
    const int w     = t >> 6;        // 0..3, i-group
    const int ln    = lane & 15;
    const int q8    = lane >> 4;

    const int s0 = chunk * 256;
    const float* kh = K + (size_t)head * DH * SEQ;
    const float* vh = V + (size_t)head * DH * SEQ;

    __shared__ __align__(16) float kbuf[2][64 * 32];   // 8 KB each
    __shared__ __align__(16) float vbuf[2][64 * 32];   // 8 KB each

    // staging map: thread t stages rows r = q*32 + (t>>3), 16B-slot t&7
    const int srow  = t >> 3;        // 0..31
    const int sslot = t & 7;         // 0..7
    const int wslot = sslot ^ (srow & 7);   // swizzled write slot

    float4 stK[2], stV[2];
    #pragma unroll
    for (int q = 0; q < 2; ++q) {
        const int r = q * 32 + srow;
        stK[q] = *(const float4*)(kh + (size_t)r * SEQ + s0 + sslot * 4);
        stV[q] = *(const float4*)(vh + (size_t)r * SEQ + s0 + sslot * 4);
    }
    #pragma unroll
    for (int q = 0; q < 2; ++q) {
        const int r = q * 32 + srow;
        *(float4*)(&kbuf[0][r * 32 + wslot * 4]) = stK[q];
        *(float4*)(&vbuf[0][r * 32 + wslot * 4]) = stV[q];
    }
    __syncthreads();

    floatx4 acc[4];
    #pragma unroll
    for (int jt = 0; jt < 4; ++jt) acc[jt] = (floatx4){0.f, 0.f, 0.f, 0.f};
    float zacc = 0.f;

    const int rA = 16 * w + ln;      // this lane's A row

    #pragma unroll 2
    for (int step = 0; step < 8; ++step) {
        const int p = step & 1;
        // 1. issue next step's global loads early (T14 issue-early)
        if (step < 7) {
            const int sb = s0 + (step + 1) * 32;
            #pragma unroll
            for (int q = 0; q < 2; ++q) {
                const int r = q * 32 + srow;
                stK[q] = *(const float4*)(kh + (size_t)r * SEQ + sb + sslot * 4);
                stV[q] = *(const float4*)(vh + (size_t)r * SEQ + sb + sslot * 4);
            }
        }
        // 2. compute current step from LDS buf p
        float e[8];
        #pragma unroll
        for (int eo = 0; eo < 2; ++eo) {
            const int sl = ((q8 * 2 + eo) ^ (rA & 7)) * 4;
            const float4 kv = *(const float4*)(&kbuf[p][rA * 32 + sl]);
            e[eo * 4 + 0] = __expf(kv.x);
            e[eo * 4 + 1] = __expf(kv.y);
            e[eo * 4 + 2] = __expf(kv.z);
            e[eo * 4 + 3] = __expf(kv.w);
        }
        zacc += e[0]+e[1]+e[2]+e[3]+e[4]+e[5]+e[6]+e[7];
        half8 ah;
        #pragma unroll
        for (int x = 0; x < 8; ++x) ah[x] = (_Float16)e[x];
        #pragma unroll
        for (int jt = 0; jt < 4; ++jt) {
            const int rB = 16 * jt + ln;
            half8 bh;
            #pragma unroll
            for (int eo = 0; eo < 2; ++eo) {
                const int sl = ((q8 * 2 + eo) ^ (rB & 7)) * 4;
                const float4 vv = *(const float4*)(&vbuf[p][rB * 32 + sl]);
                bh[eo * 4 + 0] = (_Float16)vv.x;
                bh[eo * 4 + 1] = (_Float16)vv.y;
                bh[eo * 4 + 2] = (_Float16)vv.z;
                bh[eo * 4 + 3] = (_Float16)vv.w;
            }
            acc[jt] = __builtin_amdgcn_mfma_f32_16x16x32_f16(ah, bh, acc[jt], 0, 0, 0);
        }
        // 3. write staged regs into the other buffer (write-late), one barrier
        if (step < 7) {
            #pragma unroll
            for (int q = 0; q < 2; ++q) {
                const int r = q * 32 + srow;
                *(float4*)(&kbuf[p ^ 1][r * 32 + wslot * 4]) = stK[q];
                *(float4*)(&vbuf[p ^ 1][r * 32 + wslot * 4]) = stV[q];
            }
            __syncthreads();
        }
    }

    float* ph = partial + (size_t)(head * NCHUNK + chunk) * DH * DH;
    #pragma unroll
    for (int jt = 0; jt < 4; ++jt) {
        #pragma unroll
        for (int rr = 0; rr < 4; ++rr) {
            const int i = 16 * w + q8 * 4 + rr;
            const int j = 16 * jt + ln;
            ph[i * DH + j] = acc[jt][rr];
        }
    }

    // Z[i] = sum over the 4 q8 col-groups (lanes ln, ln+16, ln+32, ln+48)
    zacc += __shfl_xor(zacc, 16);
    zacc += __shfl_xor(zacc, 32);
    if (lane < 16)
        Zp[(head * NCHUNK + chunk) * DH + 16 * w + ln] = zacc;
}

// ---------------------------------------------------------------------------
// Kernel 2: czT[head][j][i] = (1/Z_i) * sum_c partial[head][c][i][j]  (fp16)
// grid 512 blocks: (head, 4-row i-group) -> 2 blocks/CU.
// Per-c loads are 1 KiB contiguous per block. Z summed redundantly per
// thread (32 L2-broadcast scalar loads) -> no LDS, no barriers.
// ---------------------------------------------------------------------------
__global__ __launch_bounds__(256)
void reduce_kernel(const float* __restrict__ partial, const float* __restrict__ Zp,
                   _Float16* __restrict__ czT)
{
    const int h  = blockIdx.x >> 4;
    const int ig = blockIdx.x & 15;       // i rows [4*ig, 4*ig+4)
    const int t  = threadIdx.x;
    const int il = t >> 6;                // 0..3
    const int j  = t & 63;
    const int i  = 4 * ig + il;

    const float* ph = partial + (size_t)h * NCHUNK * DH * DH + i * DH + j;
    float sum = 0.f;
    #pragma unroll
    for (int c = 0; c < NCHUNK; ++c)
        sum += ph[(size_t)c * DH * DH];

    float z = 0.f;
    #pragma unroll
    for (int c = 0; c < NCHUNK; ++c)
        z += Zp[(h * NCHUNK + c) * DH + i];

    czT[(size_t)h * DH * DH + j * DH + i] = (_Float16)(sum / z);
}

// ---------------------------------------------------------------------------
// Kernel 3: out[j][s] = rw[s] * sum_i czT[j][i] * eq[i][s]
// grid (64 s-blocks x 32 heads) = 2048 blocks, 2 rounds of 64 s.
// 32x32x16 MFMA: C col spans 32 s -> every store = two full 128-B lines.
//   A[m=lane&31][k=8*(lane>>5)+j], B[n=lane&31][k=8*(lane>>5)+j]
//   C/D: col=lane&31, row=(reg&3)+8*(reg>>2)+4*(lane>>5)   [m74/m101]
// (unchanged this round)
// ---------------------------------------------------------------------------
__global__ __launch_bounds__(256)
void out_kernel(const float* __restrict__ Q, const _Float16* __restrict__ czT,
                float* __restrict__ out)
{
    const int head = blockIdx.y;
    const int sb   = blockIdx.x;
    const int t    = threadIdx.x;
    const int lane = t & 63;
    const int w    = t >> 6;
    const int l31  = lane & 31;
    const int lh   = lane >> 5;
    const int jw   = 32 * (w & 1);        // wave's j-strip
    const int sw   = 32 * (w >> 1);       // wave's s-strip within round

    __shared__ __align__(16) float    qf[64 * 68];   // fp32 natural [i][s]
    __shared__ __align__(16) _Float16 eqT[64 * 64];  // [s][i] fp16, XOR-chunk swizzle
    __shared__ __align__(16) float    wred[64 * 4];  // [s][4 partials]

    const float* qh = Q + (size_t)head * DH * SEQ;
    const int r0 = t >> 4;
    const int sc = 4 * (t & 15);
    const int s0 = sb * 128;

    float4 pq[4];
    #pragma unroll
    for (int p = 0; p < 4; ++p)
        pq[p] = *(const float4*)(qh + (size_t)(r0 + 16 * p) * SEQ + s0 + sc);

    // persistent A-frags from global czT (L2-hot, 8 KiB/head)
    const _Float16* ch = czT + (size_t)head * DH * DH;
    half8 afr[4];
    #pragma unroll
    for (int st = 0; st < 4; ++st)
        afr[st] = *(const half8*)(ch + (jw + l31) * DH + st * 16 + lh * 8);

    for (int r = 0; r < 2; ++r) {
        #pragma unroll
        for (int p = 0; p < 4; ++p)
            *(float4*)(qf + (r0 + 16 * p) * 68 + sc) = pq[p];
        // issue next round's loads right after consumption
        if (r < 1) {
            #pragma unroll
            for (int p = 0; p < 4; ++p)
                pq[p] = *(const float4*)(qh + (size_t)(r0 + 16 * p) * SEQ
                                         + s0 + 64 + sc);
        }
        __syncthreads();
        // transpose + exp + column-sum partials
        {
            const int s  = t & 63;
            const int cg = t >> 6;
            float wsum = 0.f;
            #pragma unroll
            for (int h2 = 0; h2 < 2; ++h2) {
                const int cc = cg + 4 * h2;
                half8 p8;
                #pragma unroll
                for (int jj = 0; jj < 8; ++jj) {
                    const float e = __expf(qf[(8 * cc + jj) * 68 + s]);
                    wsum += e;
                    p8[jj] = (_Float16)e;
                }
                *(half8*)(eqT + s * 64 + ((cc ^ (s & 7)) * 8)) = p8;
            }
            wred[s * 4 + cg] = wsum;
        }
        __syncthreads();
        // per-lane softmax denom for this lane's s column
        const float4 wv = *(const float4*)(wred + (sw + l31) * 4);
        const float rw = QSCALE / (wv.x + wv.y + wv.z + wv.w);
        // 32x32 tile: 4 K-steps of 16
        floatx16 acc = {};
        #pragma unroll
        for (int st = 0; st < 4; ++st) {
            const int s2 = sw + l31;
            const int cc = 2 * st + lh;
            const half8 b = *(const half8*)(eqT + s2 * 64 + ((cc ^ (s2 & 7)) * 8));
            acc = __builtin_amdgcn_mfma_f32_32x32x16_f16(afr[st], b, acc, 0, 0, 0);
        }
        // full-line stores: lanes 0..31 cover 128 B at row j1, lanes 32..63 row j1+4
        float* oh = out + (size_t)head * DH * SEQ + s0 + r * 64;
        #pragma unroll
        for (int rg = 0; rg < 16; ++rg) {
            const int j = jw + (rg & 3) + 8 * (rg >> 2) + 4 * lh;
            oh[(size_t)j * SEQ + sw + l31] = acc[rg] * rw;
        }
    }
}

extern "C" void kernel_launch(void* const* d_in, const int* in_sizes, int n_in,
                              void* d_out, int out_size, void* d_ws, size_t ws_size,
                              hipStream_t stream)
{
    const float* q = (const float*)d_in[0];
    const float* k = (const float*)d_in[1];
    const float* v = (const float*)d_in[2];
    float* out = (float*)d_out;

    float*    partial = (float*)d_ws;                           // 16 MiB
    float*    Zp      = partial + BHEADS * NCHUNK * DH * DH;    // 256 KiB
    _Float16* czT     = (_Float16*)(Zp + BHEADS * NCHUNK * DH); // 256 KiB

    ctx_partial_kernel<<<dim3(NCHUNK, BHEADS), 256, 0, stream>>>(k, v, partial, Zp);
    reduce_kernel<<<BHEADS * 16, 256, 0, stream>>>(partial, Zp, czT);
    out_kernel<<<dim3(64, BHEADS), 256, 0, stream>>>(q, czT, out);
}

// Round 6
// 243.657 us; speedup vs baseline: 1.0135x; 1.0135x over previous
//
#include <hip/hip_runtime.h>
#include <math.h>

// LinearAttend: B=4, N=8, D=64, S=8192, fp32 in/out.
// out[j,s] = (QSCALE/W_s) * sum_i (ctx[i,j]/Z_i) * exp(q[i,s])
//   ctx[i,j] = sum_s exp(k[i,s]) * v[j,s],  Z_i = sum_s exp(k[i,s])
// 3-kernel pipeline, zero atomics:
//   1) ctx_partial: 32-way split-K fp16-MFMA partials. Double-buffered
//      LDS tiles staged via global_load_lds width-16 (DMA path: ZERO
//      staging VGPRs / ds_writes -- round-4's reg-staged variant spilled
//      ~320 B/thread of scratch, WRITE_SIZE 16.6->100 MB). 16 KB/block
//      in flight during each compute phase; one barrier per step.
//      Swizzle on the SOURCE side (m173): linear LDS dest + pre-swizzled
//      per-lane global col + swizzled read (read code = round-4 verified).
//      [Resubmission: round-5 bench died to container infra failure; code
//       audited for hang/fault mechanisms (barrier uniformity, bounds,
//       LDS races, swizzle algebra) -- none found. Identical resubmit.]
//   2) reduce: 512 blocks, sum 32 chunk-partials, fold 1/Z, fp16 czT[j][i].
//   3) out: 32x32x16 fp16 MFMA -> full-cacheline stores (unchanged).

typedef _Float16 half8 __attribute__((ext_vector_type(8)));
typedef float floatx4 __attribute__((ext_vector_type(4)));
typedef float floatx16 __attribute__((ext_vector_type(16)));

constexpr int BHEADS = 32;
constexpr int DH     = 64;
constexpr int SEQ    = 8192;
constexpr int NCHUNK = 32;          // split-K chunks of 256 s
constexpr float QSCALE = 0.125f;    // 64^-0.5

// async global->LDS, 16 B per lane, lane i lands at ldsbase + 16*i (m104)
__device__ __forceinline__ void gload_lds16(const float* g, float* l)
{
    __builtin_amdgcn_global_load_lds(
        (const __attribute__((address_space(1))) void*)g,
        (__attribute__((address_space(3))) void*)l, 16, 0, 0);
}

// ---------------------------------------------------------------------------
// Kernel 1: partial[head][chunk][i][j] = sum_{s in chunk} e[i,s]*v[j,s]
//           Zp[head][chunk][i]         = sum_{s in chunk} e[i,s]
// grid (32 chunks x 32 heads) = 1024 blocks x 256 threads (4 waves).
// Wave w owns i-rows [16w,16w+16) over the full 256-s chunk.
// 8 K-steps of BK=32 s. Per step:
//   1. issue step t+1's 4 global_load_lds_dwordx4 (wave stages its 16
//      rows of K and V; 16 KB/block in flight)
//   2. compute step t from LDS buf p (swizzled ds_read, exp, cvt, 4 MFMA)
//   3. __syncthreads (drains vmcnt -> t+1 tile ready)
// LDS tiles [64 rows][32 floats] linear; each load instr covers 8 rows x
// 8 16B-slots (lane i -> row base+i/8, slot i%8). Source col pre-swizzled:
// LDS slot s of row r holds global slot s ^ (r&7); reads use the same XOR.
// Fragment map (16x16x32 f16): lane = ln + 16*q8 holds
//   A[m=ln][k=q8*8..+8) = exp(K[16w+ln][s0+st*32+q8*8..])
//   B[n=ln][k=...]      =      V[16jt+ln][s0+st*32+q8*8..]
//   C/D: col=ln, row=q8*4+reg   [m89/m91 verified layout]
// ---------------------------------------------------------------------------
__global__ __launch_bounds__(256)
void ctx_partial_kernel(const float* __restrict__ K, const float* __restrict__ V,
                        float* __restrict__ partial, float* __restrict__ Zp)
{
    const int head  = blockIdx.y;
    const int chunk = blockIdx.x;
    const int t     = threadIdx.x;
    const int lane  = t & 63;
    const int w     = t >> 6;        // 0..3, i-group
    const int ln    = lane & 15;
    const int q8    = lane >> 4;

    const int s0 = chunk * 256;
    const float* kh = K + (size_t)head * DH * SEQ;
    const float* vh = V + (size_t)head * DH * SEQ;

    __shared__ __align__(16) float kbuf[2][64 * 32];   // 8 KB each
    __shared__ __align__(16) float vbuf[2][64 * 32];   // 8 KB each

    // staging map: wave w stages rows [16w,16w+16) of K and V.
    // instr 0: rows 16w..16w+8, instr 1: rows +8..+16 ((r+8)&7 == r&7,
    // so the per-lane swizzled col is shared by both instrs).
    const int rl = 16 * w + (lane >> 3);          // instr-0 row of this lane
    const int sg = (lane & 7) ^ (rl & 7);         // pre-swizzled global slot
    const float* kg0 = kh + (size_t)rl * SEQ + s0 + sg * 4;
    const float* kg1 = kg0 + (size_t)8 * SEQ;
    const float* vg0 = vh + (size_t)rl * SEQ + s0 + sg * 4;
    const float* vg1 = vg0 + (size_t)8 * SEQ;

#define STAGE(pb, off)                                          \
    do {                                                        \
        gload_lds16(kg0 + (off), &kbuf[pb][(16 * w) * 32]);     \
        gload_lds16(kg1 + (off), &kbuf[pb][(16 * w + 8) * 32]); \
        gload_lds16(vg0 + (off), &vbuf[pb][(16 * w) * 32]);     \
        gload_lds16(vg1 + (off), &vbuf[pb][(16 * w + 8) * 32]); \
    } while (0)

    STAGE(0, 0);
    __syncthreads();

    floatx4 acc[4];
    #pragma unroll
    for (int jt = 0; jt < 4; ++jt) acc[jt] = (floatx4){0.f, 0.f, 0.f, 0.f};
    float zacc = 0.f;

    const int rA = 16 * w + ln;      // this lane's A row

    #pragma unroll
    for (int step = 0; step < 8; ++step) {
        const int p = step & 1;      // compile-time (full unroll)
        // 1. issue next step's DMA loads first (latency hidden under compute)
        if (step < 7) STAGE(p ^ 1, (step + 1) * 32);
        // 2. compute current step from LDS buf p
        float e[8];
        #pragma unroll
        for (int eo = 0; eo < 2; ++eo) {
            const int sl = ((q8 * 2 + eo) ^ (rA & 7)) * 4;
            const float4 kv = *(const float4*)(&kbuf[p][rA * 32 + sl]);
            e[eo * 4 + 0] = __expf(kv.x);
            e[eo * 4 + 1] = __expf(kv.y);
            e[eo * 4 + 2] = __expf(kv.z);
            e[eo * 4 + 3] = __expf(kv.w);
        }
        zacc += e[0]+e[1]+e[2]+e[3]+e[4]+e[5]+e[6]+e[7];
        half8 ah;
        #pragma unroll
        for (int x = 0; x < 8; ++x) ah[x] = (_Float16)e[x];
        #pragma unroll
        for (int jt = 0; jt < 4; ++jt) {
            const int rB = 16 * jt + ln;
            half8 bh;
            #pragma unroll
            for (int eo = 0; eo < 2; ++eo) {
                const int sl = ((q8 * 2 + eo) ^ (rB & 7)) * 4;
                const float4 vv = *(const float4*)(&vbuf[p][rB * 32 + sl]);
                bh[eo * 4 + 0] = (_Float16)vv.x;
                bh[eo * 4 + 1] = (_Float16)vv.y;
                bh[eo * 4 + 2] = (_Float16)vv.z;
                bh[eo * 4 + 3] = (_Float16)vv.w;
            }
            acc[jt] = __builtin_amdgcn_mfma_f32_16x16x32_f16(ah, bh, acc[jt], 0, 0, 0);
        }
        // 3. barrier: drains vmcnt(0) -> step t+1 tile resident; also
        //    protects buf[p] from being re-staged at step t+1.
        if (step < 7) __syncthreads();
    }
#undef STAGE

    float* ph = partial + (size_t)(head * NCHUNK + chunk) * DH * DH;
    #pragma unroll
    for (int jt = 0; jt < 4; ++jt) {
        #pragma unroll
        for (int rr = 0; rr < 4; ++rr) {
            const int i = 16 * w + q8 * 4 + rr;
            const int j = 16 * jt + ln;
            ph[i * DH + j] = acc[jt][rr];
        }
    }

    // Z[i] = sum over the 4 q8 col-groups (lanes ln, ln+16, ln+32, ln+48)
    zacc += __shfl_xor(zacc, 16);
    zacc += __shfl_xor(zacc, 32);
    if (lane < 16)
        Zp[(head * NCHUNK + chunk) * DH + 16 * w + ln] = zacc;
}

// ---------------------------------------------------------------------------
// Kernel 2: czT[head][j][i] = (1/Z_i) * sum_c partial[head][c][i][j]  (fp16)
// grid 512 blocks: (head, 4-row i-group) -> 2 blocks/CU.
// Per-c loads are 1 KiB contiguous per block. Z summed redundantly per
// thread (32 L2-broadcast scalar loads) -> no LDS, no barriers.
// ---------------------------------------------------------------------------
__global__ __launch_bounds__(256)
void reduce_kernel(const float* __restrict__ partial, const float* __restrict__ Zp,
                   _Float16* __restrict__ czT)
{
    const int h  = blockIdx.x >> 4;
    const int ig = blockIdx.x & 15;       // i rows [4*ig, 4*ig+4)
    const int t  = threadIdx.x;
    const int il = t >> 6;                // 0..3
    const int j  = t & 63;
    const int i  = 4 * ig + il;

    const float* ph = partial + (size_t)h * NCHUNK * DH * DH + i * DH + j;
    float sum = 0.f;
    #pragma unroll
    for (int c = 0; c < NCHUNK; ++c)
        sum += ph[(size_t)c * DH * DH];

    float z = 0.f;
    #pragma unroll
    for (int c = 0; c < NCHUNK; ++c)
        z += Zp[(h * NCHUNK + c) * DH + i];

    czT[(size_t)h * DH * DH + j * DH + i] = (_Float16)(sum / z);
}

// ---------------------------------------------------------------------------
// Kernel 3: out[j][s] = rw[s] * sum_i czT[j][i] * eq[i][s]
// grid (64 s-blocks x 32 heads) = 2048 blocks, 2 rounds of 64 s.
// 32x32x16 MFMA: C col spans 32 s -> every store = two full 128-B lines.
//   A[m=lane&31][k=8*(lane>>5)+j], B[n=lane&31][k=8*(lane>>5)+j]
//   C/D: col=lane&31, row=(reg&3)+8*(reg>>2)+4*(lane>>5)   [m74/m101]
// (unchanged this round)
// ---------------------------------------------------------------------------
__global__ __launch_bounds__(256)
void out_kernel(const float* __restrict__ Q, const _Float16* __restrict__ czT,
                float* __restrict__ out)
{
    const int head = blockIdx.y;
    const int sb   = blockIdx.x;
    const int t    = threadIdx.x;
    const int lane = t & 63;
    const int w    = t >> 6;
    const int l31  = lane & 31;
    const int lh   = lane >> 5;
    const int jw   = 32 * (w & 1);        // wave's j-strip
    const int sw   = 32 * (w >> 1);       // wave's s-strip within round

    __shared__ __align__(16) float    qf[64 * 68];   // fp32 natural [i][s]
    __shared__ __align__(16) _Float16 eqT[64 * 64];  // [s][i] fp16, XOR-chunk swizzle
    __shared__ __align__(16) float    wred[64 * 4];  // [s][4 partials]

    const float* qh = Q + (size_t)head * DH * SEQ;
    const int r0 = t >> 4;
    const int sc = 4 * (t & 15);
    const int s0 = sb * 128;

    float4 pq[4];
    #pragma unroll
    for (int p = 0; p < 4; ++p)
        pq[p] = *(const float4*)(qh + (size_t)(r0 + 16 * p) * SEQ + s0 + sc);

    // persistent A-frags from global czT (L2-hot, 8 KiB/head)
    const _Float16* ch = czT + (size_t)head * DH * DH;
    half8 afr[4];
    #pragma unroll
    for (int st = 0; st < 4; ++st)
        afr[st] = *(const half8*)(ch + (jw + l31) * DH + st * 16 + lh * 8);

    for (int r = 0; r < 2; ++r) {
        #pragma unroll
        for (int p = 0; p < 4; ++p)
            *(float4*)(qf + (r0 + 16 * p) * 68 + sc) = pq[p];
        // issue next round's loads right after consumption
        if (r < 1) {
            #pragma unroll
            for (int p = 0; p < 4; ++p)
                pq[p] = *(const float4*)(qh + (size_t)(r0 + 16 * p) * SEQ
                                         + s0 + 64 + sc);
        }
        __syncthreads();
        // transpose + exp + column-sum partials
        {
            const int s  = t & 63;
            const int cg = t >> 6;
            float wsum = 0.f;
            #pragma unroll
            for (int h2 = 0; h2 < 2; ++h2) {
                const int cc = cg + 4 * h2;
                half8 p8;
                #pragma unroll
                for (int jj = 0; jj < 8; ++jj) {
                    const float e = __expf(qf[(8 * cc + jj) * 68 + s]);
                    wsum += e;
                    p8[jj] = (_Float16)e;
                }
                *(half8*)(eqT + s * 64 + ((cc ^ (s & 7)) * 8)) = p8;
            }
            wred[s * 4 + cg] = wsum;
        }
        __syncthreads();
        // per-lane softmax denom for this lane's s column
        const float4 wv = *(const float4*)(wred + (sw + l31) * 4);
        const float rw = QSCALE / (wv.x + wv.y + wv.z + wv.w);
        // 32x32 tile: 4 K-steps of 16
        floatx16 acc = {};
        #pragma unroll
        for (int st = 0; st < 4; ++st) {
            const int s2 = sw + l31;
            const int cc = 2 * st + lh;
            const half8 b = *(const half8*)(eqT + s2 * 64 + ((cc ^ (s2 & 7)) * 8));
            acc = __builtin_amdgcn_mfma_f32_32x32x16_f16(afr[st], b, acc, 0, 0, 0);
        }
        // full-line stores: lanes 0..31 cover 128 B at row j1, lanes 32..63 row j1+4
        float* oh = out + (size_t)head * DH * SEQ + s0 + r * 64;
        #pragma unroll
        for (int rg = 0; rg < 16; ++rg) {
            const int j = jw + (rg & 3) + 8 * (rg >> 2) + 4 * lh;
            oh[(size_t)j * SEQ + sw + l31] = acc[rg] * rw;
        }
    }
}

extern "C" void kernel_launch(void* const* d_in, const int* in_sizes, int n_in,
                              void* d_out, int out_size, void* d_ws, size_t ws_size,
                              hipStream_t stream)
{
    const float* q = (const float*)d_in[0];
    const float* k = (const float*)d_in[1];
    const float* v = (const float*)d_in[2];
    float* out = (float*)d_out;

    float*    partial = (float*)d_ws;                           // 16 MiB
    float*    Zp      = partial + BHEADS * NCHUNK * DH * DH;    // 256 KiB
    _Float16* czT     = (_Float16*)(Zp + BHEADS * NCHUNK * DH); // 256 KiB

    ctx_partial_kernel<<<dim3(NCHUNK, BHEADS), 256, 0, stream>>>(k, v, partial, Zp);
    reduce_kernel<<<BHEADS * 16, 256, 0, stream>>>(partial, Zp, czT);
    out_kernel<<<dim3(64, BHEADS), 256, 0, stream>>>(q, czT, out);
}

// Round 7
// 236.584 us; speedup vs baseline: 1.0438x; 1.0299x over previous
//
#include <hip/hip_runtime.h>
#include <math.h>

// LinearAttend: B=4, N=8, D=64, S=8192, fp32 in/out.
// out[j,s] = (QSCALE/W_s) * sum_i (ctx[i,j]/Z_i) * exp(q[i,s])
//   ctx[i,j] = sum_s exp(k[i,s]) * v[j,s],  Z_i = sum_s exp(k[i,s])
// 3-kernel pipeline, zero atomics:
//   1) ctx_partial: 32-way split-K fp16-MFMA partials, DMA-staged dbuf
//      LDS (round-6 verified, 59 us, byte-identical this round).
//   2) reduce: 512 blocks, sum 32 chunk-partials, fold 1/Z, fp16 czT[j][i]
//      (byte-identical this round).
//   3) out: REWRITTEN: zero-LDS zero-barrier register-direct MFMA.
//      B-fragments (exp(q)) built from per-k coalesced dword loads
//      (32 lanes x consecutive s = full 128-B line), exp in-register,
//      W_s from the same exp values via one shfl_xor(32). Grid 4096
//      blocks (16/CU) for deep TLP. Replaces 26 KB LDS transpose +
//      4 barriers/block of the old design.

typedef _Float16 half8 __attribute__((ext_vector_type(8)));
typedef float floatx4 __attribute__((ext_vector_type(4)));
typedef float floatx16 __attribute__((ext_vector_type(16)));

constexpr int BHEADS = 32;
constexpr int DH     = 64;
constexpr int SEQ    = 8192;
constexpr int NCHUNK = 32;          // split-K chunks of 256 s
constexpr float QSCALE = 0.125f;    // 64^-0.5

// async global->LDS, 16 B per lane, lane i lands at ldsbase + 16*i (m104)
__device__ __forceinline__ void gload_lds16(const float* g, float* l)
{
    __builtin_amdgcn_global_load_lds(
        (const __attribute__((address_space(1))) void*)g,
        (__attribute__((address_space(3))) void*)l, 16, 0, 0);
}

// ---------------------------------------------------------------------------
// Kernel 1: partial[head][chunk][i][j] = sum_{s in chunk} e[i,s]*v[j,s]
//           Zp[head][chunk][i]         = sum_{s in chunk} e[i,s]
// grid (32 chunks x 32 heads) = 1024 blocks x 256 threads (4 waves).
// [byte-identical to round 6: 59 us, VGPR 44, WRITE 16.6 MB]
// ---------------------------------------------------------------------------
__global__ __launch_bounds__(256)
void ctx_partial_kernel(const float* __restrict__ K, const float* __restrict__ V,
                        float* __restrict__ partial, float* __restrict__ Zp)
{
    const int head  = blockIdx.y;
    const int chunk = blockIdx.x;
    const int t     = threadIdx.x;
    const int lane  = t & 63;
    const int w     = t >> 6;        // 0..3, i-group
    const int ln    = lane & 15;
    const int q8    = lane >> 4;

    const int s0 = chunk * 256;
    const float* kh = K + (size_t)head * DH * SEQ;
    const float* vh = V + (size_t)head * DH * SEQ;

    __shared__ __align__(16) float kbuf[2][64 * 32];   // 8 KB each
    __shared__ __align__(16) float vbuf[2][64 * 32];   // 8 KB each

    // staging map: wave w stages rows [16w,16w+16) of K and V.
    const int rl = 16 * w + (lane >> 3);          // instr-0 row of this lane
    const int sg = (lane & 7) ^ (rl & 7);         // pre-swizzled global slot
    const float* kg0 = kh + (size_t)rl * SEQ + s0 + sg * 4;
    const float* kg1 = kg0 + (size_t)8 * SEQ;
    const float* vg0 = vh + (size_t)rl * SEQ + s0 + sg * 4;
    const float* vg1 = vg0 + (size_t)8 * SEQ;

#define STAGE(pb, off)                                          \
    do {                                                        \
        gload_lds16(kg0 + (off), &kbuf[pb][(16 * w) * 32]);     \
        gload_lds16(kg1 + (off), &kbuf[pb][(16 * w + 8) * 32]); \
        gload_lds16(vg0 + (off), &vbuf[pb][(16 * w) * 32]);     \
        gload_lds16(vg1 + (off), &vbuf[pb][(16 * w + 8) * 32]); \
    } while (0)

    STAGE(0, 0);
    __syncthreads();

    floatx4 acc[4];
    #pragma unroll
    for (int jt = 0; jt < 4; ++jt) acc[jt] = (floatx4){0.f, 0.f, 0.f, 0.f};
    float zacc = 0.f;

    const int rA = 16 * w + ln;      // this lane's A row

    #pragma unroll
    for (int step = 0; step < 8; ++step) {
        const int p = step & 1;      // compile-time (full unroll)
        // 1. issue next step's DMA loads first (latency hidden under compute)
        if (step < 7) STAGE(p ^ 1, (step + 1) * 32);
        // 2. compute current step from LDS buf p
        float e[8];
        #pragma unroll
        for (int eo = 0; eo < 2; ++eo) {
            const int sl = ((q8 * 2 + eo) ^ (rA & 7)) * 4;
            const float4 kv = *(const float4*)(&kbuf[p][rA * 32 + sl]);
            e[eo * 4 + 0] = __expf(kv.x);
            e[eo * 4 + 1] = __expf(kv.y);
            e[eo * 4 + 2] = __expf(kv.z);
            e[eo * 4 + 3] = __expf(kv.w);
        }
        zacc += e[0]+e[1]+e[2]+e[3]+e[4]+e[5]+e[6]+e[7];
        half8 ah;
        #pragma unroll
        for (int x = 0; x < 8; ++x) ah[x] = (_Float16)e[x];
        #pragma unroll
        for (int jt = 0; jt < 4; ++jt) {
            const int rB = 16 * jt + ln;
            half8 bh;
            #pragma unroll
            for (int eo = 0; eo < 2; ++eo) {
                const int sl = ((q8 * 2 + eo) ^ (rB & 7)) * 4;
                const float4 vv = *(const float4*)(&vbuf[p][rB * 32 + sl]);
                bh[eo * 4 + 0] = (_Float16)vv.x;
                bh[eo * 4 + 1] = (_Float16)vv.y;
                bh[eo * 4 + 2] = (_Float16)vv.z;
                bh[eo * 4 + 3] = (_Float16)vv.w;
            }
            acc[jt] = __builtin_amdgcn_mfma_f32_16x16x32_f16(ah, bh, acc[jt], 0, 0, 0);
        }
        // 3. barrier: drains vmcnt(0) -> step t+1 tile resident.
        if (step < 7) __syncthreads();
    }
#undef STAGE

    float* ph = partial + (size_t)(head * NCHUNK + chunk) * DH * DH;
    #pragma unroll
    for (int jt = 0; jt < 4; ++jt) {
        #pragma unroll
        for (int rr = 0; rr < 4; ++rr) {
            const int i = 16 * w + q8 * 4 + rr;
            const int j = 16 * jt + ln;
            ph[i * DH + j] = acc[jt][rr];
        }
    }

    // Z[i] = sum over the 4 q8 col-groups (lanes ln, ln+16, ln+32, ln+48)
    zacc += __shfl_xor(zacc, 16);
    zacc += __shfl_xor(zacc, 32);
    if (lane < 16)
        Zp[(head * NCHUNK + chunk) * DH + 16 * w + ln] = zacc;
}

// ---------------------------------------------------------------------------
// Kernel 2: czT[head][j][i] = (1/Z_i) * sum_c partial[head][c][i][j]  (fp16)
// grid 512 blocks: (head, 4-row i-group). [byte-identical this round]
// ---------------------------------------------------------------------------
__global__ __launch_bounds__(256)
void reduce_kernel(const float* __restrict__ partial, const float* __restrict__ Zp,
                   _Float16* __restrict__ czT)
{
    const int h  = blockIdx.x >> 4;
    const int ig = blockIdx.x & 15;       // i rows [4*ig, 4*ig+4)
    const int t  = threadIdx.x;
    const int il = t >> 6;                // 0..3
    const int j  = t & 63;
    const int i  = 4 * ig + il;

    const float* ph = partial + (size_t)h * NCHUNK * DH * DH + i * DH + j;
    float sum = 0.f;
    #pragma unroll
    for (int c = 0; c < NCHUNK; ++c)
        sum += ph[(size_t)c * DH * DH];

    float z = 0.f;
    #pragma unroll
    for (int c = 0; c < NCHUNK; ++c)
        z += Zp[(h * NCHUNK + c) * DH + i];

    czT[(size_t)h * DH * DH + j * DH + i] = (_Float16)(sum / z);
}

// ---------------------------------------------------------------------------
// Kernel 3 (REWRITTEN): out[j][s] = rw[s] * sum_i czT[j][i] * eq[i][s]
// grid (128 s-blocks x 32 heads) = 4096 blocks x 256 thr (4 waves).
// Wave w: j-strip jw=32*(w&1), s-strip s0 = 64*sb + 32*(w>>1).
// ZERO LDS, ZERO BARRIERS: per k-step, the 8 B-fragment elements are
// fetched as 8 coalesced dword loads (lanes 0-31 read q[i][s0..s0+32) =
// one 128-B line; lanes 32-63 the i+8 row), exp'd in-register, packed
// to fp16, fed to 32x32x16 MFMA. W_s accumulates from the same exp
// values (lane covers the lh-half of i); one shfl_xor(32) completes it.
//   A[m=l31][k=8*lh+kj] = czT[jw+m][st*16+8*lh+kj]   (fp16, contiguous)
//   B[n=l31][k=8*lh+kj] = exp(q[st*16+8*lh+kj][s0+n])
//   C/D: col=l31 (=s), row=(reg&3)+8*(reg>>2)+4*lh (=j)   [m74/m101]
// Stores: each of 16 stores = 2 full 128-B lines (rows j, j+4).
// ---------------------------------------------------------------------------
__global__ __launch_bounds__(256)
void out_kernel(const float* __restrict__ Q, const _Float16* __restrict__ czT,
                float* __restrict__ out)
{
    const int head = blockIdx.y;
    const int sb   = blockIdx.x;          // 0..127, 64 s per block
    const int t    = threadIdx.x;
    const int lane = t & 63;
    const int w    = t >> 6;
    const int l31  = lane & 31;
    const int lh   = lane >> 5;
    const int jw   = 32 * (w & 1);        // wave's j-strip
    const int s0   = sb * 64 + 32 * (w >> 1);   // wave's s-strip

    // per-lane Q column base: row i is qh[i*SEQ]
    const float* qh = Q + (size_t)head * DH * SEQ + s0 + l31;

    // persistent A-frags from global czT (L2-hot, 8 KiB/head)
    const _Float16* ch = czT + (size_t)head * DH * DH;
    half8 afr[4];
    #pragma unroll
    for (int st = 0; st < 4; ++st)
        afr[st] = *(const half8*)(ch + (jw + l31) * DH + st * 16 + lh * 8);

    floatx16 acc = {};
    float wsum = 0.f;
    #pragma unroll
    for (int st = 0; st < 4; ++st) {
        // this lane's 8 k-elements: i = st*16 + 8*lh + kj
        float e[8];
        #pragma unroll
        for (int kj = 0; kj < 8; ++kj) {
            const float qv = qh[(size_t)(16 * st + 8 * lh + kj) * SEQ];
            e[kj] = __expf(qv);
        }
        half8 b;
        #pragma unroll
        for (int kj = 0; kj < 8; ++kj) {
            wsum += e[kj];
            b[kj] = (_Float16)e[kj];
        }
        acc = __builtin_amdgcn_mfma_f32_32x32x16_f16(afr[st], b, acc, 0, 0, 0);
    }
    // full softmax denom over all 64 i: lane covered lh-half; partner lane
    // (same l31, other lh) covered the rest.
    wsum += __shfl_xor(wsum, 32);
    const float rw = QSCALE / wsum;

    float* oh = out + (size_t)head * DH * SEQ + s0 + l31;
    #pragma unroll
    for (int rg = 0; rg < 16; ++rg) {
        const int j = jw + (rg & 3) + 8 * (rg >> 2) + 4 * lh;
        oh[(size_t)j * SEQ] = acc[rg] * rw;
    }
}

extern "C" void kernel_launch(void* const* d_in, const int* in_sizes, int n_in,
                              void* d_out, int out_size, void* d_ws, size_t ws_size,
                              hipStream_t stream)
{
    const float* q = (const float*)d_in[0];
    const float* k = (const float*)d_in[1];
    const float* v = (const float*)d_in[2];
    float* out = (float*)d_out;

    float*    partial = (float*)d_ws;                           // 16 MiB
    float*    Zp      = partial + BHEADS * NCHUNK * DH * DH;    // 256 KiB
    _Float16* czT     = (_Float16*)(Zp + BHEADS * NCHUNK * DH); // 256 KiB

    ctx_partial_kernel<<<dim3(NCHUNK, BHEADS), 256, 0, stream>>>(k, v, partial, Zp);
    reduce_kernel<<<BHEADS * 16, 256, 0, stream>>>(partial, Zp, czT);
    out_kernel<<<dim3(128, BHEADS), 256, 0, stream>>>(q, czT, out);
}